// Round 6
// baseline (355.403 us; speedup 1.0000x reference)
//
#include <hip/hip_runtime.h>
#include <math.h>

#define BB 2
#define TT 1024
#define DD 1024
#define HH 16
#define HS 64
#define NROWS (BB*TT)   // 2048

typedef _Float16 f16;
typedef __attribute__((ext_vector_type(8))) _Float16 half8;
typedef __attribute__((ext_vector_type(4))) _Float16 half4;
typedef __attribute__((ext_vector_type(4))) float f32x4;

constexpr float EPS   = 1e-5f;
constexpr float SCALE = 8.0f;   // faithful bug: scores * sqrt(HS)

__device__ __forceinline__ void load_lds16(const f16* g, f16* l) {
    __builtin_amdgcn_global_load_lds(
        (const __attribute__((address_space(1))) unsigned int*)g,
        (__attribute__((address_space(3))) unsigned int*)l, 16, 0, 0);
}

// XCD-aware bijective swizzle of the linear block id (total % 8 == 0).
__device__ __forceinline__ int xcd_swizzle(int lin, int total) {
    if ((total & 7) == 0) {
        const int chunk = total >> 3;
        lin = (lin & 7) * chunk + (lin >> 3);
    }
    return lin;
}

// ---------------- RMSNorm: fp32 in -> fp16 out ----------------
__global__ __launch_bounds__(256) void rmsnorm_kernel(const float* __restrict__ x,
                                                      const float* __restrict__ w,
                                                      f16* __restrict__ out) {
    const int row = blockIdx.x;
    const int tid = threadIdx.x;
    const float* xr = x + (size_t)row * DD;

    float4 xv = reinterpret_cast<const float4*>(xr)[tid];
    float ss = xv.x*xv.x + xv.y*xv.y + xv.z*xv.z + xv.w*xv.w;

    __shared__ float red[256];
    red[tid] = ss; __syncthreads();
    for (int s = 128; s > 0; s >>= 1) {
        if (tid < s) red[tid] += red[tid + s];
        __syncthreads();
    }
    const float inv = rsqrtf(red[0] * (1.0f / DD) + EPS);

    float4 wv = reinterpret_cast<const float4*>(w)[tid];
    half4 o;
    o.x = (f16)(xv.x * inv * wv.x);
    o.y = (f16)(xv.y * inv * wv.y);
    o.z = (f16)(xv.z * inv * wv.z);
    o.w = (f16)(xv.w * inv * wv.w);
    *reinterpret_cast<half4*>(&out[(size_t)row * DD + tid * 4]) = o;
}

// ---------------- weight transpose+convert: fp32 [K][N] (or (H,D,HS)) -> fp16 [N][K] ----------------
template<bool HEADW>
__global__ __launch_bounds__(256) void wtrans(const float* __restrict__ W,
                                              f16* __restrict__ Wt,
                                              int K, int N) {
    __shared__ float t[64][65];
    const int k0 = blockIdx.x * 64;
    const int n0 = blockIdx.y * 64;
    const int tid = threadIdx.x;

    #pragma unroll
    for (int r = 0; r < 4; ++r) {
        const int idx = tid + r * 256;
        const int kl  = idx >> 4;
        const int nl4 = (idx & 15) * 4;
        const float* gp;
        if (HEADW) {
            gp = W + ((size_t)(n0 >> 6) * K + (k0 + kl)) * 64 + nl4;
        } else {
            gp = W + (size_t)(k0 + kl) * N + n0 + nl4;
        }
        float4 v = *reinterpret_cast<const float4*>(gp);
        t[kl][nl4 + 0] = v.x; t[kl][nl4 + 1] = v.y;
        t[kl][nl4 + 2] = v.z; t[kl][nl4 + 3] = v.w;
    }
    __syncthreads();
    #pragma unroll
    for (int r = 0; r < 4; ++r) {
        const int idx = tid + r * 256;
        const int nl  = idx >> 4;
        const int kl4 = (idx & 15) * 4;
        half4 o;
        o.x = (f16)t[kl4 + 0][nl];
        o.y = (f16)t[kl4 + 1][nl];
        o.z = (f16)t[kl4 + 2][nl];
        o.w = (f16)t[kl4 + 3][nl];
        *reinterpret_cast<half4*>(&Wt[(size_t)(n0 + nl) * K + k0 + kl4]) = o;
    }
}

__global__ void pack_bias(const float* __restrict__ a, const float* __restrict__ b,
                          const float* __restrict__ c, float* __restrict__ o) {
    const int i = blockIdx.x * 256 + threadIdx.x;
    if (i < 1024) { o[i] = a[i]; o[i + 1024] = b[i]; o[i + 2048] = c[i]; }
}

// ---------------- fp16 MFMA GEMM, 128-wide N tiles: C = A @ Bt^T ----------------
// 3-buffer LDS pipeline, depth-2 prefetch, counted vmcnt (loads stay in flight
// across barriers; only the final K-step drains to 0).
template<int BM, int EPI, bool HEADOUT, bool SPLITA, bool OHALF, bool OUT2>
__global__ __launch_bounds__(256, 2) void gemm_mfma(
    const f16* __restrict__ A1,
    const f16* __restrict__ A2,
    const f16* __restrict__ Bt,
    const float* __restrict__ bias,
    const float* __restrict__ resid,
    float* __restrict__ outF,
    f16* __restrict__ outH,
    f16* __restrict__ outH2,
    int N, int K, int splitN)
{
    constexpr int BK = 32;
    constexpr int MI = 4;
    constexpr int NI = (BM == 128) ? 4 : 2;
    constexpr int WN = (BM == 128) ? 64 : 32;
    constexpr int ASLOT = BM * 4;
    constexpr int AINST = ASLOT / 256;

    __shared__ f16 ldsA[3][ASLOT * 8];
    __shared__ f16 ldsB[3][512 * 8];

    const int tid  = threadIdx.x;
    const int lane = tid & 63;
    const int wid  = tid >> 6;
    const int gx = gridDim.x;
    const int lin = xcd_swizzle(blockIdx.y * gx + blockIdx.x, gx * gridDim.y);
    const int m0 = (lin / gx) * BM;
    const int n0 = (lin % gx) * 128;
    const int wm = (BM == 128) ? (wid >> 1) : 0;
    const int wn = (BM == 128) ? (wid & 1) : wid;

    const f16* Aptr = (SPLITA && n0 >= splitN) ? A2 : A1;

    f32x4 acc[MI][NI];
    #pragma unroll
    for (int i = 0; i < MI; ++i)
        #pragma unroll
        for (int j = 0; j < NI; ++j)
            acc[i][j] = (f32x4){0.f, 0.f, 0.f, 0.f};

    // 4 global_load_lds instructions per thread per stage()
    auto stage = [&](int buf, int kt) {
        const int k0 = kt * BK;
        #pragma unroll
        for (int i = 0; i < AINST; ++i) {
            const int s   = (wid * AINST + i) * 64 + lane;
            const int kh  = s / BM;
            const int row = s % BM;
            load_lds16(Aptr + (size_t)(m0 + row) * K + (k0 + kh * 8),
                       &ldsA[buf][s * 8]);
        }
        #pragma unroll
        for (int i = 0; i < 2; ++i) {
            const int s   = (wid * 2 + i) * 64 + lane;
            const int kh  = s >> 7;
            const int col = s & 127;
            load_lds16(Bt + (size_t)(n0 + col) * K + (k0 + kh * 8),
                       &ldsB[buf][s * 8]);
        }
    };

    const int NT = K / BK;
    stage(0, 0);
    stage(1, 1);
    int cur = 0;
    const int l15 = lane & 15, l4 = lane >> 4;
    for (int kt = 0; kt < NT; ++kt) {
        // wait for tile kt's 4 loads (leave tile kt+1's 4 in flight), sync waves
        if (kt + 1 < NT)
            asm volatile("s_waitcnt vmcnt(4)" ::: "memory");
        else
            asm volatile("s_waitcnt vmcnt(0)" ::: "memory");
        __builtin_amdgcn_s_barrier();
        asm volatile("" ::: "memory");
        // prefetch tile kt+2 into the buffer consumed in iteration kt-1
        if (kt + 2 < NT) {
            int stg = cur + 2; if (stg >= 3) stg -= 3;
            stage(stg, kt + 2);
        }
        half8 af[MI], bfr[NI];
        #pragma unroll
        for (int mi = 0; mi < MI; ++mi)
            af[mi] = *reinterpret_cast<const half8*>(
                &ldsA[cur][(l4 * BM + wm * 64 + mi * 16 + l15) * 8]);
        #pragma unroll
        for (int ni = 0; ni < NI; ++ni)
            bfr[ni] = *reinterpret_cast<const half8*>(
                &ldsB[cur][(l4 * 128 + wn * WN + ni * 16 + l15) * 8]);
        #pragma unroll
        for (int mi = 0; mi < MI; ++mi)
            #pragma unroll
            for (int ni = 0; ni < NI; ++ni)
                acc[mi][ni] = __builtin_amdgcn_mfma_f32_16x16x32_f16(
                    af[mi], bfr[ni], acc[mi][ni], 0, 0, 0);
        ++cur; if (cur == 3) cur = 0;
    }

    #pragma unroll
    for (int mi = 0; mi < MI; ++mi) {
        #pragma unroll
        for (int ni = 0; ni < NI; ++ni) {
            #pragma unroll
            for (int r = 0; r < 4; ++r) {
                const int row = m0 + wm * 64 + mi * 16 + l4 * 4 + r;
                const int col = n0 + wn * WN + ni * 16 + l15;
                float v = acc[mi][ni][r];
                if (EPI >= 1) v += bias[col];
                if (EPI == 2) v = 0.5f * v * (1.0f + erff(v * 0.70710678118f));
                if (EPI == 3) v += resid[(size_t)row * N + col];
                size_t oidx;
                if (HEADOUT) {
                    const int mat = col >> 10;
                    const int h = (col >> 6) & 15, e = col & 63;
                    const int b = row >> 10, t = row & (TT - 1);
                    oidx = (size_t)mat * ((size_t)NROWS * DD)
                         + ((size_t)((b * HH + h) * TT + t)) * HS + e;
                } else {
                    oidx = (size_t)row * N + col;
                }
                if (OHALF) outH[oidx] = (f16)v;
                else       outF[oidx] = v;
                if (OUT2)  outH2[oidx] = (f16)v;
            }
        }
    }
}

// ---------------- fp16 MFMA GEMM, 64x64 tiles, BK=64 (for N=1024 projections) ----
// Same 3-buffer counted-vmcnt pipeline; 4 waves as 2x2, each wave 32x32.
template<int EPI, bool OHALF, bool OUT2>
__global__ __launch_bounds__(256, 2) void gemm_mfma64(
    const f16* __restrict__ A,
    const f16* __restrict__ Bt,
    const float* __restrict__ bias,
    const float* __restrict__ resid,
    float* __restrict__ outF,
    f16* __restrict__ outH,
    f16* __restrict__ outH2,
    int N, int K)
{
    constexpr int BK = 64;

    __shared__ f16 ldsA[3][512 * 8];   // slot = kh*64 + row, 8 halfs each
    __shared__ f16 ldsB[3][512 * 8];

    const int tid  = threadIdx.x;
    const int lane = tid & 63;
    const int wid  = tid >> 6;
    const int gx = gridDim.x;
    const int lin = xcd_swizzle(blockIdx.y * gx + blockIdx.x, gx * gridDim.y);
    const int m0 = (lin / gx) * 64;
    const int n0 = (lin % gx) * 64;
    const int wm = wid >> 1, wn = wid & 1;
    const int l15 = lane & 15, l4 = lane >> 4;

    f32x4 acc[2][2];
    #pragma unroll
    for (int i = 0; i < 2; ++i)
        #pragma unroll
        for (int j = 0; j < 2; ++j)
            acc[i][j] = (f32x4){0.f, 0.f, 0.f, 0.f};

    // 4 global_load_lds instructions per thread per stage()
    auto stage = [&](int buf, int kt) {
        const int k0 = kt * BK;
        #pragma unroll
        for (int i = 0; i < 2; ++i) {
            const int kh = wid * 2 + i;          // 0..7
            load_lds16(A  + (size_t)(m0 + lane) * K + (k0 + kh * 8),
                       &ldsA[buf][(kh * 64 + lane) * 8]);
            load_lds16(Bt + (size_t)(n0 + lane) * K + (k0 + kh * 8),
                       &ldsB[buf][(kh * 64 + lane) * 8]);
        }
    };

    const int NT = K / BK;
    stage(0, 0);
    stage(1, 1);
    int cur = 0;
    for (int kt = 0; kt < NT; ++kt) {
        if (kt + 1 < NT)
            asm volatile("s_waitcnt vmcnt(4)" ::: "memory");
        else
            asm volatile("s_waitcnt vmcnt(0)" ::: "memory");
        __builtin_amdgcn_s_barrier();
        asm volatile("" ::: "memory");
        if (kt + 2 < NT) {
            int stg = cur + 2; if (stg >= 3) stg -= 3;
            stage(stg, kt + 2);
        }
        #pragma unroll
        for (int ks = 0; ks < 2; ++ks) {
            half8 af[2], bfr[2];
            #pragma unroll
            for (int mi = 0; mi < 2; ++mi)
                af[mi] = *reinterpret_cast<const half8*>(
                    &ldsA[cur][((ks * 4 + l4) * 64 + wm * 32 + mi * 16 + l15) * 8]);
            #pragma unroll
            for (int ni = 0; ni < 2; ++ni)
                bfr[ni] = *reinterpret_cast<const half8*>(
                    &ldsB[cur][((ks * 4 + l4) * 64 + wn * 32 + ni * 16 + l15) * 8]);
            #pragma unroll
            for (int mi = 0; mi < 2; ++mi)
                #pragma unroll
                for (int ni = 0; ni < 2; ++ni)
                    acc[mi][ni] = __builtin_amdgcn_mfma_f32_16x16x32_f16(
                        af[mi], bfr[ni], acc[mi][ni], 0, 0, 0);
        }
        ++cur; if (cur == 3) cur = 0;
    }

    #pragma unroll
    for (int mi = 0; mi < 2; ++mi) {
        #pragma unroll
        for (int ni = 0; ni < 2; ++ni) {
            #pragma unroll
            for (int r = 0; r < 4; ++r) {
                const int row = m0 + wm * 32 + mi * 16 + l4 * 4 + r;
                const int col = n0 + wn * 32 + ni * 16 + l15;
                float v = acc[mi][ni][r];
                if (EPI >= 1) v += bias[col];
                if (EPI == 2) v = 0.5f * v * (1.0f + erff(v * 0.70710678118f));
                if (EPI == 3) v += resid[(size_t)row * N + col];
                const size_t oidx = (size_t)row * N + col;
                if (OHALF) outH[oidx] = (f16)v;
                else       outF[oidx] = v;
                if (OUT2)  outH2[oidx] = (f16)v;
            }
        }
    }
}

// ---------------- MFMA flash attention (fp16 in/out, fp32 softmax/acc) ----------------
template<bool CAUSAL>
__global__ __launch_bounds__(256) void attn_mfma(const f16* __restrict__ Q,
                                                 const f16* __restrict__ Kg,
                                                 const f16* __restrict__ Vg,
                                                 f16* __restrict__ O) {
    const int iq  = blockIdx.x;
    const int bh  = blockIdx.y;
    const int tid = threadIdx.x;
    const int lane = tid & 63;
    const int w   = tid >> 6;
    const int l15 = lane & 15, l4 = lane >> 4;

    __shared__ f16 Ks[512 * 8];      // slot-major: slot = eh*64 + s
    __shared__ f16 VT[64 * 72];      // VT[e][s], row stride 72
    __shared__ f16 Ps[4][16 * 72];   // per-wave P[q'][s], row stride 72

    const f16* qb = Q  + ((size_t)bh * TT + (size_t)iq * 64) * HS;
    const f16* kb = Kg + (size_t)bh * TT * HS;
    const f16* vb = Vg + (size_t)bh * TT * HS;

    half8 qf[2];
    #pragma unroll
    for (int ks = 0; ks < 2; ++ks)
        qf[ks] = *reinterpret_cast<const half8*>(
            qb + (size_t)(w * 16 + l15) * HS + ks * 32 + l4 * 8);

    f32x4 oacc[4];
    #pragma unroll
    for (int ni = 0; ni < 4; ++ni) oacc[ni] = (f32x4){0.f, 0.f, 0.f, 0.f};
    float m_run[4], l_run[4];
    #pragma unroll
    for (int r = 0; r < 4; ++r) { m_run[r] = -1e30f; l_run[r] = 0.f; }

    const int sp  = lane & 31;
    const int ehv = lane >> 5;
    const int c0  = w * 16 + ehv * 8;

    const int ntiles = CAUSAL ? (iq + 1) : (TT / 64);
    for (int js = 0; js < ntiles; ++js) {
        __syncthreads();

        #pragma unroll
        for (int i = 0; i < 2; ++i) {
            const int slot = (w * 2 + i) * 64 + lane;
            load_lds16(kb + (size_t)(js * 64 + (slot & 63)) * HS + (slot >> 6) * 8,
                       &Ks[slot * 8]);
        }
        {
            const f16* vrow = vb + (size_t)(js * 64 + 2 * sp) * HS + c0;
            uint4 r0 = *reinterpret_cast<const uint4*>(vrow);
            uint4 r1 = *reinterpret_cast<const uint4*>(vrow + HS);
            const unsigned rc0[4] = {r0.x, r0.y, r0.z, r0.w};
            const unsigned rc1[4] = {r1.x, r1.y, r1.z, r1.w};
            #pragma unroll
            for (int i = 0; i < 8; ++i) {
                const unsigned lo = (i & 1) ? (rc0[i >> 1] >> 16) : (rc0[i >> 1] & 0xffffu);
                const unsigned hi = (i & 1) ? (rc1[i >> 1] >> 16) : (rc1[i >> 1] & 0xffffu);
                *reinterpret_cast<unsigned*>(&VT[(c0 + i) * 72 + 2 * sp]) = lo | (hi << 16);
            }
        }
        __syncthreads();

        f32x4 sacc[4];
        #pragma unroll
        for (int ni = 0; ni < 4; ++ni) sacc[ni] = (f32x4){0.f, 0.f, 0.f, 0.f};
        #pragma unroll
        for (int ks = 0; ks < 2; ++ks) {
            #pragma unroll
            for (int ni = 0; ni < 4; ++ni) {
                half8 kf = *reinterpret_cast<const half8*>(
                    &Ks[((ks * 4 + l4) * 64 + ni * 16 + l15) * 8]);
                sacc[ni] = __builtin_amdgcn_mfma_f32_16x16x32_f16(qf[ks], kf, sacc[ni], 0, 0, 0);
            }
        }

        float sv[4][4];
        #pragma unroll
        for (int ni = 0; ni < 4; ++ni) {
            #pragma unroll
            for (int r = 0; r < 4; ++r) {
                float x = sacc[ni][r] * SCALE;
                if (CAUSAL && js == iq) {
                    const int sg = js * 64 + ni * 16 + l15;
                    const int qg = iq * 64 + w * 16 + l4 * 4 + r;
                    if (sg > qg) x = -1e30f;
                }
                sv[ni][r] = x;
            }
        }

        #pragma unroll
        for (int r = 0; r < 4; ++r) {
            float rm = fmaxf(fmaxf(sv[0][r], sv[1][r]), fmaxf(sv[2][r], sv[3][r]));
            rm = fmaxf(rm, __shfl_xor(rm, 1));
            rm = fmaxf(rm, __shfl_xor(rm, 2));
            rm = fmaxf(rm, __shfl_xor(rm, 4));
            rm = fmaxf(rm, __shfl_xor(rm, 8));
            const float mnew = fmaxf(m_run[r], rm);
            const float corr = __expf(m_run[r] - mnew);
            float p0 = __expf(sv[0][r] - mnew);
            float p1 = __expf(sv[1][r] - mnew);
            float p2 = __expf(sv[2][r] - mnew);
            float p3 = __expf(sv[3][r] - mnew);
            float sum = p0 + p1 + p2 + p3;
            sum += __shfl_xor(sum, 1);
            sum += __shfl_xor(sum, 2);
            sum += __shfl_xor(sum, 4);
            sum += __shfl_xor(sum, 8);
            l_run[r] = l_run[r] * corr + sum;
            m_run[r] = mnew;
            #pragma unroll
            for (int ni = 0; ni < 4; ++ni) oacc[ni][r] *= corr;
            f16* prow = &Ps[w][(l4 * 4 + r) * 72];
            prow[ 0 + l15] = (f16)p0;
            prow[16 + l15] = (f16)p1;
            prow[32 + l15] = (f16)p2;
            prow[48 + l15] = (f16)p3;
        }

        #pragma unroll
        for (int ks = 0; ks < 2; ++ks) {
            half8 pf = *reinterpret_cast<const half8*>(&Ps[w][l15 * 72 + ks * 32 + l4 * 8]);
            #pragma unroll
            for (int ni = 0; ni < 4; ++ni) {
                half8 vf = *reinterpret_cast<const half8*>(
                    &VT[(ni * 16 + l15) * 72 + ks * 32 + l4 * 8]);
                oacc[ni] = __builtin_amdgcn_mfma_f32_16x16x32_f16(pf, vf, oacc[ni], 0, 0, 0);
            }
        }
    }

    const int b = bh >> 4, h = bh & (HH - 1);
    #pragma unroll
    for (int r = 0; r < 4; ++r) {
        const float inv = 1.0f / l_run[r];
        const int t = iq * 64 + w * 16 + l4 * 4 + r;
        #pragma unroll
        for (int ni = 0; ni < 4; ++ni)
            O[((size_t)(b * TT + t)) * DD + h * HS + ni * 16 + l15] =
                (f16)(oacc[ni][r] * inv);
    }
}

extern "C" void kernel_launch(void* const* d_in, const int* in_sizes, int n_in,
                              void* d_out, int out_size, void* d_ws, size_t ws_size,
                              hipStream_t stream) {
    const float* src      = (const float*)d_in[0];
    const float* att      = (const float*)d_in[1];
    const float* wq_m     = (const float*)d_in[2];
    const float* wk_m     = (const float*)d_in[3];
    const float* wv_m     = (const float*)d_in[4];
    const float* proj_m_w = (const float*)d_in[5];
    const float* proj_m_b = (const float*)d_in[6];
    const float* wq_f     = (const float*)d_in[7];
    const float* wk_f     = (const float*)d_in[8];
    const float* wv_f     = (const float*)d_in[9];
    const float* bq_f     = (const float*)d_in[10];
    const float* bk_f     = (const float*)d_in[11];
    const float* bv_f     = (const float*)d_in[12];
    const float* proj_f_w = (const float*)d_in[13];
    const float* proj_f_b = (const float*)d_in[14];
    const float* w1       = (const float*)d_in[15];
    const float* b1       = (const float*)d_in[16];
    const float* w2       = (const float*)d_in[17];
    const float* b2       = (const float*)d_in[18];
    const float* norm_w   = (const float*)d_in[19];

    const size_t M_ = 1024 * 1024;
    f16* wsb = (f16*)d_ws;
    f16* wt_qkvm = wsb;                 // [3072][1024]
    f16* wt_projm = wsb + 3 * M_;       // [1024][1024]
    f16* wt_qkvf = wsb + 4 * M_;        // [3072][1024]
    f16* wt_projf = wsb + 7 * M_;       // [1024][1024]
    f16* wt_w1   = wsb + 8 * M_;        // [4096][1024]
    f16* wt_w2   = wsb + 12 * M_;       // [1024][4096]
    f16* xn  = wsb + 16 * M_;           // [2048][1024]
    f16* qkv = wsb + 18 * M_;           // q,k,v each 2M
    f16* ao  = wsb + 24 * M_;           // [2048][1024]
    f16* h1  = wsb + 18 * M_;           // [2048][4096] (overlays qkv+ao in FFN phase)
    float* m_out = (float*)(wsb + 26 * M_);   // [2048][1024] fp32
    f16* mo_h  = (f16*)d_out;                                   // [2048][1024] f16
    float* biascat = (float*)((char*)d_out + 4 * 1024 * 1024);  // 3072 floats
    float* f_out = (float*)d_out;
    float* outp  = (float*)d_out;
    (void)ws_size; (void)in_sizes; (void)n_in;

    const dim3 blk(256);
    const int BIG = 1 << 30;

    // ---- weight prep ----
    pack_bias<<<dim3(4), blk, 0, stream>>>(bq_f, bk_f, bv_f, biascat);
    wtrans<true ><<<dim3(16, 16), blk, 0, stream>>>(wq_m, wt_qkvm + 0 * M_, 1024, 1024);
    wtrans<true ><<<dim3(16, 16), blk, 0, stream>>>(wk_m, wt_qkvm + 1 * M_, 1024, 1024);
    wtrans<true ><<<dim3(16, 16), blk, 0, stream>>>(wv_m, wt_qkvm + 2 * M_, 1024, 1024);
    wtrans<false><<<dim3(16, 16), blk, 0, stream>>>(proj_m_w, wt_projm, 1024, 1024);
    wtrans<true ><<<dim3(16, 16), blk, 0, stream>>>(wq_f, wt_qkvf + 0 * M_, 1024, 1024);
    wtrans<true ><<<dim3(16, 16), blk, 0, stream>>>(wk_f, wt_qkvf + 1 * M_, 1024, 1024);
    wtrans<true ><<<dim3(16, 16), blk, 0, stream>>>(wv_f, wt_qkvf + 2 * M_, 1024, 1024);
    wtrans<false><<<dim3(16, 16), blk, 0, stream>>>(proj_f_w, wt_projf, 1024, 1024);
    wtrans<false><<<dim3(16, 64), blk, 0, stream>>>(w1, wt_w1, 1024, 4096);
    wtrans<false><<<dim3(64, 16), blk, 0, stream>>>(w2, wt_w2, 4096, 1024);

    // ---- masked self-attention block ----
    rmsnorm_kernel<<<dim3(NROWS), blk, 0, stream>>>(src, norm_w, xn);
    gemm_mfma<128, 0, true, false, true, false><<<dim3(24, 16), blk, 0, stream>>>(
        xn, nullptr, wt_qkvm, nullptr, nullptr, nullptr, qkv, nullptr, 3072, 1024, BIG);
    attn_mfma<true><<<dim3(16, 32), blk, 0, stream>>>(qkv, qkv + 2 * M_, qkv + 4 * M_, ao);
    gemm_mfma64<3, false, true><<<dim3(16, 32), blk, 0, stream>>>(
        ao, wt_projm, proj_m_b, src, m_out, nullptr, mo_h, 1024, 1024);

    // ---- cross attention block: q/k from rmsnorm(att), v from m_out ----
    rmsnorm_kernel<<<dim3(NROWS), blk, 0, stream>>>(att, norm_w, xn);
    gemm_mfma<128, 1, true, true, true, false><<<dim3(24, 16), blk, 0, stream>>>(
        xn, mo_h, wt_qkvf, biascat, nullptr, nullptr, qkv, nullptr, 3072, 1024, 2048);
    attn_mfma<false><<<dim3(16, 32), blk, 0, stream>>>(qkv, qkv + 2 * M_, qkv + 4 * M_, ao);
    gemm_mfma64<3, false, false><<<dim3(16, 32), blk, 0, stream>>>(
        ao, wt_projf, proj_f_b, m_out, f_out, nullptr, nullptr, 1024, 1024);

    // ---- FFN block ----
    rmsnorm_kernel<<<dim3(NROWS), blk, 0, stream>>>(f_out, norm_w, xn);
    gemm_mfma<128, 2, false, false, true, false><<<dim3(32, 16), blk, 0, stream>>>(
        xn, nullptr, wt_w1, b1, nullptr, nullptr, h1, nullptr, 4096, 1024, BIG);
    gemm_mfma64<3, false, false><<<dim3(16, 32), blk, 0, stream>>>(
        h1, wt_w2, b2, f_out, outp, nullptr, nullptr, 1024, 4096);
}

// Round 7
// 338.957 us; speedup vs baseline: 1.0485x; 1.0485x over previous
//
#include <hip/hip_runtime.h>
#include <math.h>

#define BB 2
#define TT 1024
#define DD 1024
#define HH 16
#define HS 64
#define NROWS (BB*TT)   // 2048

typedef _Float16 f16;
typedef __attribute__((ext_vector_type(8))) _Float16 half8;
typedef __attribute__((ext_vector_type(4))) _Float16 half4;
typedef __attribute__((ext_vector_type(4))) float f32x4;

constexpr float EPS   = 1e-5f;
constexpr float SCALE = 8.0f;   // faithful bug: scores * sqrt(HS)

__device__ __forceinline__ void load_lds16(const f16* g, f16* l) {
    __builtin_amdgcn_global_load_lds(
        (const __attribute__((address_space(1))) unsigned int*)g,
        (__attribute__((address_space(3))) unsigned int*)l, 16, 0, 0);
}

// XCD-aware bijective swizzle of the linear block id (total % 8 == 0).
__device__ __forceinline__ int xcd_swizzle(int lin, int total) {
    if ((total & 7) == 0) {
        const int chunk = total >> 3;
        lin = (lin & 7) * chunk + (lin >> 3);
    }
    return lin;
}

// ---------------- RMSNorm: fp32 in -> fp16 out ----------------
__global__ __launch_bounds__(256) void rmsnorm_kernel(const float* __restrict__ x,
                                                      const float* __restrict__ w,
                                                      f16* __restrict__ out) {
    const int row = blockIdx.x;
    const int tid = threadIdx.x;
    const float* xr = x + (size_t)row * DD;

    float4 xv = reinterpret_cast<const float4*>(xr)[tid];
    float ss = xv.x*xv.x + xv.y*xv.y + xv.z*xv.z + xv.w*xv.w;

    __shared__ float red[256];
    red[tid] = ss; __syncthreads();
    for (int s = 128; s > 0; s >>= 1) {
        if (tid < s) red[tid] += red[tid + s];
        __syncthreads();
    }
    const float inv = rsqrtf(red[0] * (1.0f / DD) + EPS);

    float4 wv = reinterpret_cast<const float4*>(w)[tid];
    half4 o;
    o.x = (f16)(xv.x * inv * wv.x);
    o.y = (f16)(xv.y * inv * wv.y);
    o.z = (f16)(xv.z * inv * wv.z);
    o.w = (f16)(xv.w * inv * wv.w);
    *reinterpret_cast<half4*>(&out[(size_t)row * DD + tid * 4]) = o;
}

// ---------------- weight transpose+convert: fp32 [K][N] (or (H,D,HS)) -> fp16 [N][K] ----------------
template<bool HEADW>
__global__ __launch_bounds__(256) void wtrans(const float* __restrict__ W,
                                              f16* __restrict__ Wt,
                                              int K, int N) {
    __shared__ float t[64][65];
    const int k0 = blockIdx.x * 64;
    const int n0 = blockIdx.y * 64;
    const int tid = threadIdx.x;

    #pragma unroll
    for (int r = 0; r < 4; ++r) {
        const int idx = tid + r * 256;
        const int kl  = idx >> 4;
        const int nl4 = (idx & 15) * 4;
        const float* gp;
        if (HEADW) {
            gp = W + ((size_t)(n0 >> 6) * K + (k0 + kl)) * 64 + nl4;
        } else {
            gp = W + (size_t)(k0 + kl) * N + n0 + nl4;
        }
        float4 v = *reinterpret_cast<const float4*>(gp);
        t[kl][nl4 + 0] = v.x; t[kl][nl4 + 1] = v.y;
        t[kl][nl4 + 2] = v.z; t[kl][nl4 + 3] = v.w;
    }
    __syncthreads();
    #pragma unroll
    for (int r = 0; r < 4; ++r) {
        const int idx = tid + r * 256;
        const int nl  = idx >> 4;
        const int kl4 = (idx & 15) * 4;
        half4 o;
        o.x = (f16)t[kl4 + 0][nl];
        o.y = (f16)t[kl4 + 1][nl];
        o.z = (f16)t[kl4 + 2][nl];
        o.w = (f16)t[kl4 + 3][nl];
        *reinterpret_cast<half4*>(&Wt[(size_t)(n0 + nl) * K + k0 + kl4]) = o;
    }
}

__global__ void pack_bias(const float* __restrict__ a, const float* __restrict__ b,
                          const float* __restrict__ c, float* __restrict__ o) {
    const int i = blockIdx.x * 256 + threadIdx.x;
    if (i < 1024) { o[i] = a[i]; o[i + 1024] = b[i]; o[i + 2048] = c[i]; }
}

// ---------------- fp16 MFMA GEMM, 128x128 tiles, BK=32, 2-buffer ----------------
// grid (N/128, M/128, ksplit). If PARTIAL: each z computes K/gridDim.z slice and
// stores raw fp32 partials to outF + z*M*N (EPI/resid ignored).
template<int BM, int EPI, bool HEADOUT, bool SPLITA, bool OHALF, bool OUT2, bool PARTIAL>
__global__ __launch_bounds__(256, 2) void gemm_mfma(
    const f16* __restrict__ A1,
    const f16* __restrict__ A2,
    const f16* __restrict__ Bt,
    const float* __restrict__ bias,
    const float* __restrict__ resid,
    float* __restrict__ outF,
    f16* __restrict__ outH,
    f16* __restrict__ outH2,
    int N, int K, int splitN)
{
    constexpr int BK = 32;
    constexpr int MI = 4;
    constexpr int NI = (BM == 128) ? 4 : 2;
    constexpr int WN = (BM == 128) ? 64 : 32;
    constexpr int ASLOT = BM * 4;
    constexpr int AINST = ASLOT / 256;

    __shared__ f16 ldsA[2][ASLOT * 8];
    __shared__ f16 ldsB[2][512 * 8];

    const int tid  = threadIdx.x;
    const int lane = tid & 63;
    const int wid  = tid >> 6;
    const int gx = gridDim.x;
    const int lin = xcd_swizzle(blockIdx.y * gx + blockIdx.x, gx * gridDim.y);
    const int m0 = (lin / gx) * BM;
    const int n0 = (lin % gx) * 128;
    const int wm = (BM == 128) ? (wid >> 1) : 0;
    const int wn = (BM == 128) ? (wid & 1) : wid;

    const int Klen  = K / gridDim.z;
    const int kbase = blockIdx.z * Klen;

    const f16* Aptr = (SPLITA && n0 >= splitN) ? A2 : A1;

    f32x4 acc[MI][NI];
    #pragma unroll
    for (int i = 0; i < MI; ++i)
        #pragma unroll
        for (int j = 0; j < NI; ++j)
            acc[i][j] = (f32x4){0.f, 0.f, 0.f, 0.f};

    auto stage = [&](int buf, int kt) {
        const int k0 = kbase + kt * BK;
        #pragma unroll
        for (int i = 0; i < AINST; ++i) {
            const int s   = (wid * AINST + i) * 64 + lane;
            const int kh  = s / BM;
            const int row = s % BM;
            load_lds16(Aptr + (size_t)(m0 + row) * K + (k0 + kh * 8),
                       &ldsA[buf][s * 8]);
        }
        #pragma unroll
        for (int i = 0; i < 2; ++i) {
            const int s   = (wid * 2 + i) * 64 + lane;
            const int kh  = s >> 7;
            const int col = s & 127;
            load_lds16(Bt + (size_t)(n0 + col) * K + (k0 + kh * 8),
                       &ldsB[buf][s * 8]);
        }
    };

    const int NT = Klen / BK;
    stage(0, 0);
    __syncthreads();
    int cur = 0;
    const int l15 = lane & 15, l4 = lane >> 4;
    for (int kt = 0; kt < NT; ++kt) {
        if (kt + 1 < NT) stage(cur ^ 1, kt + 1);
        half8 af[MI], bfr[NI];
        #pragma unroll
        for (int mi = 0; mi < MI; ++mi)
            af[mi] = *reinterpret_cast<const half8*>(
                &ldsA[cur][(l4 * BM + wm * 64 + mi * 16 + l15) * 8]);
        #pragma unroll
        for (int ni = 0; ni < NI; ++ni)
            bfr[ni] = *reinterpret_cast<const half8*>(
                &ldsB[cur][(l4 * 128 + wn * WN + ni * 16 + l15) * 8]);
        #pragma unroll
        for (int mi = 0; mi < MI; ++mi)
            #pragma unroll
            for (int ni = 0; ni < NI; ++ni)
                acc[mi][ni] = __builtin_amdgcn_mfma_f32_16x16x32_f16(
                    af[mi], bfr[ni], acc[mi][ni], 0, 0, 0);
        __syncthreads();
        cur ^= 1;
    }

    float* pout = nullptr;
    if (PARTIAL) {
        const size_t MN = (size_t)gridDim.y * BM * N;
        pout = outF + (size_t)blockIdx.z * MN;
    }

    #pragma unroll
    for (int mi = 0; mi < MI; ++mi) {
        #pragma unroll
        for (int ni = 0; ni < NI; ++ni) {
            #pragma unroll
            for (int r = 0; r < 4; ++r) {
                const int row = m0 + wm * 64 + mi * 16 + l4 * 4 + r;
                const int col = n0 + wn * WN + ni * 16 + l15;
                float v = acc[mi][ni][r];
                if (PARTIAL) {
                    pout[(size_t)row * N + col] = v;
                    continue;
                }
                if (EPI >= 1) v += bias[col];
                if (EPI == 2) v = 0.5f * v * (1.0f + erff(v * 0.70710678118f));
                if (EPI == 3) v += resid[(size_t)row * N + col];
                size_t oidx;
                if (HEADOUT) {
                    const int mat = col >> 10;
                    const int h = (col >> 6) & 15, e = col & 63;
                    const int b = row >> 10, t = row & (TT - 1);
                    oidx = (size_t)mat * ((size_t)NROWS * DD)
                         + ((size_t)((b * HH + h) * TT + t)) * HS + e;
                } else {
                    oidx = (size_t)row * N + col;
                }
                if (OHALF) outH[oidx] = (f16)v;
                else       outF[oidx] = v;
                if (OUT2)  outH2[oidx] = (f16)v;
            }
        }
    }
}

// ---------------- split-K reduce + bias + residual epilogue ----------------
// out = sum_{s<4} part[s*MN + i] + bias[i % N] + resid[i]; optional f16 copy.
template<bool OUT2>
__global__ __launch_bounds__(256) void reduce4(const float* __restrict__ part,
                                               const float* __restrict__ bias,
                                               const float* __restrict__ resid,
                                               float* __restrict__ outF,
                                               f16* __restrict__ outH2,
                                               int N) {
    const size_t MN  = (size_t)gridDim.x * 1024;
    const size_t idx = ((size_t)blockIdx.x * 256 + threadIdx.x) * 4;
    float4 a = *reinterpret_cast<const float4*>(part + idx);
    float4 b = *reinterpret_cast<const float4*>(part + MN + idx);
    float4 c = *reinterpret_cast<const float4*>(part + 2 * MN + idx);
    float4 d = *reinterpret_cast<const float4*>(part + 3 * MN + idx);
    float4 bi = *reinterpret_cast<const float4*>(bias + (idx & (size_t)(N - 1)));
    float4 rs = *reinterpret_cast<const float4*>(resid + idx);
    float4 o;
    o.x = a.x + b.x + c.x + d.x + bi.x + rs.x;
    o.y = a.y + b.y + c.y + d.y + bi.y + rs.y;
    o.z = a.z + b.z + c.z + d.z + bi.z + rs.z;
    o.w = a.w + b.w + c.w + d.w + bi.w + rs.w;
    *reinterpret_cast<float4*>(outF + idx) = o;
    if (OUT2) {
        half4 h;
        h.x = (f16)o.x; h.y = (f16)o.y; h.z = (f16)o.z; h.w = (f16)o.w;
        *reinterpret_cast<half4*>(outH2 + idx) = h;
    }
}

// ---------------- MFMA flash attention (fp16 in/out, fp32 softmax/acc) ----------------
template<bool CAUSAL>
__global__ __launch_bounds__(256) void attn_mfma(const f16* __restrict__ Q,
                                                 const f16* __restrict__ Kg,
                                                 const f16* __restrict__ Vg,
                                                 f16* __restrict__ O) {
    const int iq  = blockIdx.x;
    const int bh  = blockIdx.y;
    const int tid = threadIdx.x;
    const int lane = tid & 63;
    const int w   = tid >> 6;
    const int l15 = lane & 15, l4 = lane >> 4;

    __shared__ f16 Ks[512 * 8];      // slot-major: slot = eh*64 + s
    __shared__ f16 VT[64 * 72];      // VT[e][s], row stride 72
    __shared__ f16 Ps[4][16 * 72];   // per-wave P[q'][s], row stride 72

    const f16* qb = Q  + ((size_t)bh * TT + (size_t)iq * 64) * HS;
    const f16* kb = Kg + (size_t)bh * TT * HS;
    const f16* vb = Vg + (size_t)bh * TT * HS;

    half8 qf[2];
    #pragma unroll
    for (int ks = 0; ks < 2; ++ks)
        qf[ks] = *reinterpret_cast<const half8*>(
            qb + (size_t)(w * 16 + l15) * HS + ks * 32 + l4 * 8);

    f32x4 oacc[4];
    #pragma unroll
    for (int ni = 0; ni < 4; ++ni) oacc[ni] = (f32x4){0.f, 0.f, 0.f, 0.f};
    float m_run[4], l_run[4];
    #pragma unroll
    for (int r = 0; r < 4; ++r) { m_run[r] = -1e30f; l_run[r] = 0.f; }

    const int sp  = lane & 31;
    const int ehv = lane >> 5;
    const int c0  = w * 16 + ehv * 8;

    const int ntiles = CAUSAL ? (iq + 1) : (TT / 64);
    for (int js = 0; js < ntiles; ++js) {
        __syncthreads();

        #pragma unroll
        for (int i = 0; i < 2; ++i) {
            const int slot = (w * 2 + i) * 64 + lane;
            load_lds16(kb + (size_t)(js * 64 + (slot & 63)) * HS + (slot >> 6) * 8,
                       &Ks[slot * 8]);
        }
        {
            const f16* vrow = vb + (size_t)(js * 64 + 2 * sp) * HS + c0;
            uint4 r0 = *reinterpret_cast<const uint4*>(vrow);
            uint4 r1 = *reinterpret_cast<const uint4*>(vrow + HS);
            const unsigned rc0[4] = {r0.x, r0.y, r0.z, r0.w};
            const unsigned rc1[4] = {r1.x, r1.y, r1.z, r1.w};
            #pragma unroll
            for (int i = 0; i < 8; ++i) {
                const unsigned lo = (i & 1) ? (rc0[i >> 1] >> 16) : (rc0[i >> 1] & 0xffffu);
                const unsigned hi = (i & 1) ? (rc1[i >> 1] >> 16) : (rc1[i >> 1] & 0xffffu);
                *reinterpret_cast<unsigned*>(&VT[(c0 + i) * 72 + 2 * sp]) = lo | (hi << 16);
            }
        }
        __syncthreads();

        f32x4 sacc[4];
        #pragma unroll
        for (int ni = 0; ni < 4; ++ni) sacc[ni] = (f32x4){0.f, 0.f, 0.f, 0.f};
        #pragma unroll
        for (int ks = 0; ks < 2; ++ks) {
            #pragma unroll
            for (int ni = 0; ni < 4; ++ni) {
                half8 kf = *reinterpret_cast<const half8*>(
                    &Ks[((ks * 4 + l4) * 64 + ni * 16 + l15) * 8]);
                sacc[ni] = __builtin_amdgcn_mfma_f32_16x16x32_f16(qf[ks], kf, sacc[ni], 0, 0, 0);
            }
        }

        float sv[4][4];
        #pragma unroll
        for (int ni = 0; ni < 4; ++ni) {
            #pragma unroll
            for (int r = 0; r < 4; ++r) {
                float x = sacc[ni][r] * SCALE;
                if (CAUSAL && js == iq) {
                    const int sg = js * 64 + ni * 16 + l15;
                    const int qg = iq * 64 + w * 16 + l4 * 4 + r;
                    if (sg > qg) x = -1e30f;
                }
                sv[ni][r] = x;
            }
        }

        #pragma unroll
        for (int r = 0; r < 4; ++r) {
            float rm = fmaxf(fmaxf(sv[0][r], sv[1][r]), fmaxf(sv[2][r], sv[3][r]));
            rm = fmaxf(rm, __shfl_xor(rm, 1));
            rm = fmaxf(rm, __shfl_xor(rm, 2));
            rm = fmaxf(rm, __shfl_xor(rm, 4));
            rm = fmaxf(rm, __shfl_xor(rm, 8));
            const float mnew = fmaxf(m_run[r], rm);
            const float corr = __expf(m_run[r] - mnew);
            float p0 = __expf(sv[0][r] - mnew);
            float p1 = __expf(sv[1][r] - mnew);
            float p2 = __expf(sv[2][r] - mnew);
            float p3 = __expf(sv[3][r] - mnew);
            float sum = p0 + p1 + p2 + p3;
            sum += __shfl_xor(sum, 1);
            sum += __shfl_xor(sum, 2);
            sum += __shfl_xor(sum, 4);
            sum += __shfl_xor(sum, 8);
            l_run[r] = l_run[r] * corr + sum;
            m_run[r] = mnew;
            #pragma unroll
            for (int ni = 0; ni < 4; ++ni) oacc[ni][r] *= corr;
            f16* prow = &Ps[w][(l4 * 4 + r) * 72];
            prow[ 0 + l15] = (f16)p0;
            prow[16 + l15] = (f16)p1;
            prow[32 + l15] = (f16)p2;
            prow[48 + l15] = (f16)p3;
        }

        #pragma unroll
        for (int ks = 0; ks < 2; ++ks) {
            half8 pf = *reinterpret_cast<const half8*>(&Ps[w][l15 * 72 + ks * 32 + l4 * 8]);
            #pragma unroll
            for (int ni = 0; ni < 4; ++ni) {
                half8 vf = *reinterpret_cast<const half8*>(
                    &VT[(ni * 16 + l15) * 72 + ks * 32 + l4 * 8]);
                oacc[ni] = __builtin_amdgcn_mfma_f32_16x16x32_f16(pf, vf, oacc[ni], 0, 0, 0);
            }
        }
    }

    const int b = bh >> 4, h = bh & (HH - 1);
    #pragma unroll
    for (int r = 0; r < 4; ++r) {
        const float inv = 1.0f / l_run[r];
        const int t = iq * 64 + w * 16 + l4 * 4 + r;
        #pragma unroll
        for (int ni = 0; ni < 4; ++ni)
            O[((size_t)(b * TT + t)) * DD + h * HS + ni * 16 + l15] =
                (f16)(oacc[ni][r] * inv);
    }
}

extern "C" void kernel_launch(void* const* d_in, const int* in_sizes, int n_in,
                              void* d_out, int out_size, void* d_ws, size_t ws_size,
                              hipStream_t stream) {
    const float* src      = (const float*)d_in[0];
    const float* att      = (const float*)d_in[1];
    const float* wq_m     = (const float*)d_in[2];
    const float* wk_m     = (const float*)d_in[3];
    const float* wv_m     = (const float*)d_in[4];
    const float* proj_m_w = (const float*)d_in[5];
    const float* proj_m_b = (const float*)d_in[6];
    const float* wq_f     = (const float*)d_in[7];
    const float* wk_f     = (const float*)d_in[8];
    const float* wv_f     = (const float*)d_in[9];
    const float* bq_f     = (const float*)d_in[10];
    const float* bk_f     = (const float*)d_in[11];
    const float* bv_f     = (const float*)d_in[12];
    const float* proj_f_w = (const float*)d_in[13];
    const float* proj_f_b = (const float*)d_in[14];
    const float* w1       = (const float*)d_in[15];
    const float* b1       = (const float*)d_in[16];
    const float* w2       = (const float*)d_in[17];
    const float* b2       = (const float*)d_in[18];
    const float* norm_w   = (const float*)d_in[19];

    const size_t M_ = 1024 * 1024;
    f16* wsb = (f16*)d_ws;
    f16* wt_qkvm = wsb;                 // [3072][1024]
    f16* wt_projm = wsb + 3 * M_;       // [1024][1024]
    f16* wt_qkvf = wsb + 4 * M_;        // [3072][1024]
    f16* wt_projf = wsb + 7 * M_;       // [1024][1024]
    f16* wt_w1   = wsb + 8 * M_;        // [4096][1024]
    f16* wt_w2   = wsb + 12 * M_;       // [1024][4096]
    f16* xn  = wsb + 16 * M_;           // [2048][1024]
    f16* qkv = wsb + 18 * M_;           // q,k,v each 2M
    f16* ao  = wsb + 24 * M_;           // [2048][1024]
    f16* h1  = wsb + 18 * M_;           // [2048][4096] (overlays qkv+ao in FFN phase)
    float* m_out = (float*)(wsb + 26 * M_);   // [2048][1024] fp32 (bytes 52..60MB)
    float* partb = (float*)(wsb + 30 * M_);   // 4 x [2048][1024] fp32 (bytes 60..92MB)
    f16* mo_h  = (f16*)d_out;                                   // [2048][1024] f16
    float* biascat = (float*)((char*)d_out + 4 * 1024 * 1024);  // 3072 floats
    float* f_out = (float*)d_out;
    float* outp  = (float*)d_out;
    (void)ws_size; (void)in_sizes; (void)n_in;

    const dim3 blk(256);
    const int BIG = 1 << 30;
    const dim3 gSPLIT(8, 16, 4);   // 512 blocks, K split 4 ways
    const dim3 gRED(2048);         // 2M elements / (256*4)

    // ---- weight prep ----
    pack_bias<<<dim3(4), blk, 0, stream>>>(bq_f, bk_f, bv_f, biascat);
    wtrans<true ><<<dim3(16, 16), blk, 0, stream>>>(wq_m, wt_qkvm + 0 * M_, 1024, 1024);
    wtrans<true ><<<dim3(16, 16), blk, 0, stream>>>(wk_m, wt_qkvm + 1 * M_, 1024, 1024);
    wtrans<true ><<<dim3(16, 16), blk, 0, stream>>>(wv_m, wt_qkvm + 2 * M_, 1024, 1024);
    wtrans<false><<<dim3(16, 16), blk, 0, stream>>>(proj_m_w, wt_projm, 1024, 1024);
    wtrans<true ><<<dim3(16, 16), blk, 0, stream>>>(wq_f, wt_qkvf + 0 * M_, 1024, 1024);
    wtrans<true ><<<dim3(16, 16), blk, 0, stream>>>(wk_f, wt_qkvf + 1 * M_, 1024, 1024);
    wtrans<true ><<<dim3(16, 16), blk, 0, stream>>>(wv_f, wt_qkvf + 2 * M_, 1024, 1024);
    wtrans<false><<<dim3(16, 16), blk, 0, stream>>>(proj_f_w, wt_projf, 1024, 1024);
    wtrans<false><<<dim3(16, 64), blk, 0, stream>>>(w1, wt_w1, 1024, 4096);
    wtrans<false><<<dim3(64, 16), blk, 0, stream>>>(w2, wt_w2, 4096, 1024);

    // ---- masked self-attention block ----
    rmsnorm_kernel<<<dim3(NROWS), blk, 0, stream>>>(src, norm_w, xn);
    gemm_mfma<128, 0, true, false, true, false, false><<<dim3(24, 16), blk, 0, stream>>>(
        xn, nullptr, wt_qkvm, nullptr, nullptr, nullptr, qkv, nullptr, 3072, 1024, BIG);
    attn_mfma<true><<<dim3(16, 32), blk, 0, stream>>>(qkv, qkv + 2 * M_, qkv + 4 * M_, ao);
    gemm_mfma<128, 0, false, false, false, false, true><<<gSPLIT, blk, 0, stream>>>(
        ao, nullptr, wt_projm, nullptr, nullptr, partb, nullptr, nullptr, 1024, 1024, BIG);
    reduce4<true><<<gRED, blk, 0, stream>>>(partb, proj_m_b, src, m_out, mo_h, 1024);

    // ---- cross attention block: q/k from rmsnorm(att), v from m_out ----
    rmsnorm_kernel<<<dim3(NROWS), blk, 0, stream>>>(att, norm_w, xn);
    gemm_mfma<128, 1, true, true, true, false, false><<<dim3(24, 16), blk, 0, stream>>>(
        xn, mo_h, wt_qkvf, biascat, nullptr, nullptr, qkv, nullptr, 3072, 1024, 2048);
    attn_mfma<false><<<dim3(16, 32), blk, 0, stream>>>(qkv, qkv + 2 * M_, qkv + 4 * M_, ao);
    gemm_mfma<128, 0, false, false, false, false, true><<<gSPLIT, blk, 0, stream>>>(
        ao, nullptr, wt_projf, nullptr, nullptr, partb, nullptr, nullptr, 1024, 1024, BIG);
    reduce4<false><<<gRED, blk, 0, stream>>>(partb, proj_f_b, m_out, f_out, nullptr, 1024);

    // ---- FFN block ----
    rmsnorm_kernel<<<dim3(NROWS), blk, 0, stream>>>(f_out, norm_w, xn);
    gemm_mfma<128, 2, false, false, true, false, false><<<dim3(32, 16), blk, 0, stream>>>(
        xn, nullptr, wt_w1, b1, nullptr, nullptr, h1, nullptr, 4096, 1024, BIG);
    gemm_mfma<128, 0, false, false, false, false, true><<<gSPLIT, blk, 0, stream>>>(
        h1, nullptr, wt_w2, nullptr, nullptr, partb, nullptr, nullptr, 1024, 4096, BIG);
    reduce4<false><<<gRED, blk, 0, stream>>>(partb, b2, f_out, outp, nullptr, 1024);
}